// Round 3
// baseline (727.616 us; speedup 1.0000x reference)
//
#include <hip/hip_runtime.h>
#include <hip/hip_bf16.h>
#include <stdint.h>

// PLE layer: T=3 tasks, B=16384 rows, I=1024, O=512, 4 shared + 2 task experts, 6 gates.
// Round 3: 8-phase-style pipelined MFMA GEMM (T2 swizzle + T4 counted vmcnt + T5 setprio).
// Geometry: BM=256 BN=128 BK=64, 8 waves (4x2), per-wave 64x64, 16 MFMA/phase, 2 phases/K-tile.

#define TTASKS 3
#define BROWS  16384
#define KDIM   1024
#define ODIM   512
#define NGATE  6
#define BK     64
#define NT     (KDIM / BK)   // 16

typedef __attribute__((ext_vector_type(8))) __bf16 bf16x8;
typedef __attribute__((ext_vector_type(4))) float  f32x4;

// ---------------- ws layout (identical to round 2, 171 MiB, proven) ----------------
#define XB_OFF 0
#define WT_OFF 100663296UL
#define GT_OFF 111149056UL
#define SH_OFF 112328704UL

#define MFMA_(a, bb, c) __builtin_amdgcn_mfma_f32_16x16x32_bf16(a, bb, c, 0, 0, 0)

__device__ __forceinline__ void BAR() {
  asm volatile("" ::: "memory");
  __builtin_amdgcn_s_barrier();
  asm volatile("" ::: "memory");
}

// ---------------- cvt inputs f32 -> bf16 ----------------
__global__ __launch_bounds__(256) void cvt_inputs(const float* __restrict__ x,
                                                  __bf16* __restrict__ xb) {
  size_t i = ((size_t)blockIdx.x * 256 + threadIdx.x) * 8;
  const float4* p = (const float4*)(x + i);
  float4 a = p[0], b = p[1];
  bf16x8 o = { (__bf16)a.x, (__bf16)a.y, (__bf16)a.z, (__bf16)a.w,
               (__bf16)b.x, (__bf16)b.y, (__bf16)b.z, (__bf16)b.w };
  *(bf16x8*)(xb + i) = o;
}

// ---------------- cvt + transpose weights: W[k][o] f32 -> wT[o][k] bf16 ----------------
__global__ __launch_bounds__(256) void cvt_weights(const float* __restrict__ shW,
                                                   const float* __restrict__ tkW,
                                                   __bf16* __restrict__ wT) {
  int s = blockIdx.z;
  const float* src = (s < 4) ? (shW + (size_t)s * KDIM * ODIM)
                             : (tkW + (size_t)(s - 4) * KDIM * ODIM);
  int o   = blockIdx.x * 64 + (threadIdx.x & 63);
  int sub = threadIdx.x >> 6;
#pragma unroll
  for (int kk = 0; kk < 2; ++kk) {
    int k0 = blockIdx.y * 64 + (sub * 2 + kk) * 8;
    bf16x8 v;
#pragma unroll
    for (int i = 0; i < 8; ++i)
      v[i] = (__bf16)src[(size_t)(k0 + i) * ODIM + o];
    *(bf16x8*)(wT + ((size_t)s * ODIM + o) * KDIM + k0) = v;
  }
}

// ---------------- gates: one wave per (t,b) row; f32 dots + softmax ----------------
__global__ __launch_bounds__(256) void gates_kernel(const float* __restrict__ x,
                                                    const float* __restrict__ gW,
                                                    const float* __restrict__ gb,
                                                    float* __restrict__ gates) {
  int w = blockIdx.x * 4 + (threadIdx.x >> 6);
  int lane = threadIdx.x & 63;
  int t = w >> 14, b = w & (BROWS - 1);
  const float* xr = x + ((size_t)t * BROWS + b) * KDIM;
  const float* gw = gW + (size_t)t * KDIM * NGATE;
  float d[NGATE] = {0.f, 0.f, 0.f, 0.f, 0.f, 0.f};
  for (int i = 0; i < 16; ++i) {
    int k = i * 64 + lane;
    float xv = xr[k];
#pragma unroll
    for (int j = 0; j < NGATE; ++j) d[j] += xv * gw[k * NGATE + j];
  }
#pragma unroll
  for (int j = 0; j < NGATE; ++j) {
#pragma unroll
    for (int off = 32; off > 0; off >>= 1) d[j] += __shfl_xor(d[j], off, 64);
    d[j] += gb[t * NGATE + j];
  }
  float m = d[0];
#pragma unroll
  for (int j = 1; j < NGATE; ++j) m = fmaxf(m, d[j]);
  float s = 0.f;
#pragma unroll
  for (int j = 0; j < NGATE; ++j) { d[j] = expf(d[j] - m); s += d[j]; }
  float inv = 1.f / s;
  if (lane < NGATE) {
    float v = d[0];
#pragma unroll
    for (int j = 1; j < NGATE; ++j) v = (lane == j) ? d[j] : v;
    gates[(size_t)w * NGATE + lane] = v * inv;
  }
}

// ---------------- staging: one 16 KiB half (128 rows x 64 k) via global_load_lds ----
// T2: LDS dest stays LINEAR (HW: wave-uniform base + lane*16B); the GLOBAL source
// chunk is pre-swizzled by c ^= (r&7) so reads use the same XOR (involution).
__device__ __forceinline__ void stage_half(const __bf16* __restrict__ g,
                                           __bf16* lds, int h, int tid) {
  const int wv = tid >> 6;
#pragma unroll
  for (int l = 0; l < 2; ++l) {
    const int idx = l * 512 + tid;          // 0..1023
    const int r   = h * 128 + (idx >> 3);   // row
    const int cs  = (idx & 7) ^ (r & 7);    // pre-swizzled 16B chunk
    __builtin_amdgcn_global_load_lds(
        (const __attribute__((address_space(1))) void*)(g + (size_t)r * KDIM + cs * 8),
        (__attribute__((address_space(3))) void*)(lds + h * 8192 + (l * 512 + wv * 64) * 8),
        16, 0, 0);
  }
}

// ---------------- pipelined 256x128xK GEMM core ----------------
// A rows: Ap[r*1024 + k], r=0..255. B rows (= out cols): Bp[n*1024 + k], n=0..127.
// acc[mi][ni]: 16x16 frag at rows wm*64+mi*16, cols wn*64+ni*16.
// Schedule per K-tile t (2 phases):
//  ph0: ds_read B(8)+A mi0,1(4); stage A[t+1] h0,h1; BAR; lgkm0; 16 MFMA; BAR
//  ph1: ds_read A mi2,3(4); stage B[t+2]; vmcnt(2|0); BAR; lgkm0; 16 MFMA; BAR
__device__ __forceinline__ void gemm_core(const __bf16* __restrict__ Ap,
                                          const __bf16* __restrict__ Bp,
                                          __bf16 (*As_)[256 * 64],
                                          __bf16 (*Bs_)[128 * 64],
                                          f32x4 acc[4][4]) {
  const int tid = threadIdx.x, lane = tid & 63, wv = tid >> 6;
  const int wm = wv >> 1, wn = wv & 1;
  const int lr = lane & 15, lg = lane >> 4, x7 = lr & 7;

  // prologue: A[0] (2 halves), B[0], B[1]
  stage_half(Ap,          As_[0], 0, tid);
  stage_half(Ap,          As_[0], 1, tid);
  stage_half(Bp,          Bs_[0], 0, tid);
  stage_half(Bp + BK,     Bs_[1], 0, tid);
  asm volatile("s_waitcnt vmcnt(2)" ::: "memory");  // A[0],B[0] landed; B[1] in flight
  BAR();

  for (int t = 0; t < NT; ++t) {
    const int b = t & 1;
    const __bf16* Ab = As_[b];
    const __bf16* Bb = Bs_[b];

    // ---- phase 0 ----
    bf16x8 bF[4][2];
#pragma unroll
    for (int ni = 0; ni < 4; ++ni)
#pragma unroll
      for (int ks = 0; ks < 2; ++ks)
        bF[ni][ks] = *(const bf16x8*)(Bb + (wn * 64 + ni * 16 + lr) * 64 +
                                      (((ks * 4 + lg) ^ x7) * 8));
    bf16x8 a0[2][2];
#pragma unroll
    for (int mi = 0; mi < 2; ++mi)
#pragma unroll
      for (int ks = 0; ks < 2; ++ks)
        a0[mi][ks] = *(const bf16x8*)(Ab + (wm * 64 + mi * 16 + lr) * 64 +
                                      (((ks * 4 + lg) ^ x7) * 8));
    if (t + 1 < NT) {
      stage_half(Ap + (t + 1) * BK, As_[(t + 1) & 1], 0, tid);
      stage_half(Ap + (t + 1) * BK, As_[(t + 1) & 1], 1, tid);
    }
    BAR();
    asm volatile("s_waitcnt lgkmcnt(0)" ::: "memory");
    __builtin_amdgcn_s_setprio(1);
#pragma unroll
    for (int ni = 0; ni < 4; ++ni) {
      acc[0][ni] = MFMA_(a0[0][0], bF[ni][0], acc[0][ni]);
      acc[0][ni] = MFMA_(a0[0][1], bF[ni][1], acc[0][ni]);
      acc[1][ni] = MFMA_(a0[1][0], bF[ni][0], acc[1][ni]);
      acc[1][ni] = MFMA_(a0[1][1], bF[ni][1], acc[1][ni]);
    }
    __builtin_amdgcn_s_setprio(0);
    BAR();

    // ---- phase 1 ----
    bf16x8 a1[2][2];
#pragma unroll
    for (int mi = 0; mi < 2; ++mi)
#pragma unroll
      for (int ks = 0; ks < 2; ++ks)
        a1[mi][ks] = *(const bf16x8*)(Ab + (wm * 64 + (mi + 2) * 16 + lr) * 64 +
                                      (((ks * 4 + lg) ^ x7) * 8));
    if (t + 2 < NT) {
      stage_half(Bp + (t + 2) * BK, Bs_[b], 0, tid);
      asm volatile("s_waitcnt vmcnt(2)" ::: "memory");  // A[t+1],B[t+1] landed
    } else {
      asm volatile("s_waitcnt vmcnt(0)" ::: "memory");  // tail drain
    }
    BAR();
    asm volatile("s_waitcnt lgkmcnt(0)" ::: "memory");
    __builtin_amdgcn_s_setprio(1);
#pragma unroll
    for (int ni = 0; ni < 4; ++ni) {
      acc[2][ni] = MFMA_(a1[0][0], bF[ni][0], acc[2][ni]);
      acc[2][ni] = MFMA_(a1[0][1], bF[ni][1], acc[2][ni]);
      acc[3][ni] = MFMA_(a1[1][0], bF[ni][0], acc[3][ni]);
      acc[3][ni] = MFMA_(a1[1][1], bF[ni][1], acc[3][ni]);
    }
    __builtin_amdgcn_s_setprio(0);
    BAR();
  }
}

// ---------------- shared experts: relu(x0 @ W_e + b_e) -> bf16 ----------------
__global__ __launch_bounds__(512, 2) void shared_gemm8(const __bf16* __restrict__ xb0,
                                                       const __bf16* __restrict__ wT,
                                                       const float* __restrict__ shb,
                                                       __bf16* __restrict__ shOut) {
  __shared__ __align__(16) __bf16 As_[2][256 * 64];
  __shared__ __align__(16) __bf16 Bs_[2][128 * 64];
  const int e = blockIdx.z;
  const int rowBase = blockIdx.x * 256, colBase = blockIdx.y * 128;
  const int tid = threadIdx.x, lane = tid & 63, wv = tid >> 6;
  const int wm = wv >> 1, wn = wv & 1, lr = lane & 15, lg = lane >> 4;

  f32x4 acc[4][4];
  f32x4 z = {0.f, 0.f, 0.f, 0.f};
#pragma unroll
  for (int mi = 0; mi < 4; ++mi)
#pragma unroll
    for (int ni = 0; ni < 4; ++ni) acc[mi][ni] = z;

  gemm_core(xb0 + (size_t)rowBase * KDIM,
            wT + ((size_t)e * ODIM + colBase) * KDIM, As_, Bs_, acc);

#pragma unroll
  for (int ni = 0; ni < 4; ++ni) {
    int col = colBase + wn * 64 + ni * 16 + lr;
    float bias = shb[e * ODIM + col];
#pragma unroll
    for (int mi = 0; mi < 4; ++mi)
#pragma unroll
      for (int r = 0; r < 4; ++r) {
        int row = rowBase + wm * 64 + mi * 16 + lg * 4 + r;
        float v = fmaxf(acc[mi][ni][r] + bias, 0.f);
        shOut[((size_t)e * BROWS + row) * ODIM + col] = (__bf16)v;
      }
  }
}

// ---------------- task expert 0 + gated combine with shared -> out ----------------
__global__ __launch_bounds__(512, 2) void taskA_gemm8(const __bf16* __restrict__ xb,
                                                      const __bf16* __restrict__ wT,
                                                      const float* __restrict__ tkb,
                                                      const float* __restrict__ gates,
                                                      const __bf16* __restrict__ shOut,
                                                      float* __restrict__ out) {
  __shared__ __align__(16) __bf16 As_[2][256 * 64];
  __shared__ __align__(16) __bf16 Bs_[2][128 * 64];
  const int t = blockIdx.z;
  const int rowBase = blockIdx.x * 256, colBase = blockIdx.y * 128;
  const int tid = threadIdx.x, lane = tid & 63, wv = tid >> 6;
  const int wm = wv >> 1, wn = wv & 1, lr = lane & 15, lg = lane >> 4;
  const size_t NB = (size_t)BROWS * ODIM;

  f32x4 acc[4][4];
  f32x4 z = {0.f, 0.f, 0.f, 0.f};
#pragma unroll
  for (int mi = 0; mi < 4; ++mi)
#pragma unroll
    for (int ni = 0; ni < 4; ++ni) acc[mi][ni] = z;

  gemm_core(xb + ((size_t)t * BROWS + rowBase) * KDIM,
            wT + ((size_t)(4 + t * 2) * ODIM + colBase) * KDIM, As_, Bs_, acc);

#pragma unroll
  for (int mi = 0; mi < 4; ++mi)
#pragma unroll
    for (int r = 0; r < 4; ++r) {
      int row = rowBase + wm * 64 + mi * 16 + lg * 4 + r;
      const float* gp = gates + ((size_t)t * BROWS + row) * NGATE;
      float g0 = gp[0], g1 = gp[1], g2 = gp[2], g3 = gp[3], g4 = gp[4];
#pragma unroll
      for (int ni = 0; ni < 4; ++ni) {
        int col = colBase + wn * 64 + ni * 16 + lr;
        size_t rc = (size_t)row * ODIM + col;
        float s = g0 * (float)shOut[rc] + g1 * (float)shOut[NB + rc] +
                  g2 * (float)shOut[2 * NB + rc] + g3 * (float)shOut[3 * NB + rc];
        float bias = tkb[(t * 2) * ODIM + col];
        s += g4 * fmaxf(acc[mi][ni][r] + bias, 0.f);
        out[((size_t)t * BROWS + row) * ODIM + col] = s;
      }
    }
}

// ---------------- task expert 1: out += g5 * relu(...) ----------------
__global__ __launch_bounds__(512, 2) void taskB_gemm8(const __bf16* __restrict__ xb,
                                                      const __bf16* __restrict__ wT,
                                                      const float* __restrict__ tkb,
                                                      const float* __restrict__ gates,
                                                      float* __restrict__ out) {
  __shared__ __align__(16) __bf16 As_[2][256 * 64];
  __shared__ __align__(16) __bf16 Bs_[2][128 * 64];
  const int t = blockIdx.z;
  const int rowBase = blockIdx.x * 256, colBase = blockIdx.y * 128;
  const int tid = threadIdx.x, lane = tid & 63, wv = tid >> 6;
  const int wm = wv >> 1, wn = wv & 1, lr = lane & 15, lg = lane >> 4;

  f32x4 acc[4][4];
  f32x4 z = {0.f, 0.f, 0.f, 0.f};
#pragma unroll
  for (int mi = 0; mi < 4; ++mi)
#pragma unroll
    for (int ni = 0; ni < 4; ++ni) acc[mi][ni] = z;

  gemm_core(xb + ((size_t)t * BROWS + rowBase) * KDIM,
            wT + ((size_t)(4 + t * 2 + 1) * ODIM + colBase) * KDIM, As_, Bs_, acc);

#pragma unroll
  for (int mi = 0; mi < 4; ++mi)
#pragma unroll
    for (int r = 0; r < 4; ++r) {
      int row = rowBase + wm * 64 + mi * 16 + lg * 4 + r;
      float g5 = gates[((size_t)t * BROWS + row) * NGATE + 5];
#pragma unroll
      for (int ni = 0; ni < 4; ++ni) {
        int col = colBase + wn * 64 + ni * 16 + lr;
        float bias = tkb[(t * 2 + 1) * ODIM + col];
        size_t oi = ((size_t)t * BROWS + row) * ODIM + col;
        out[oi] += g5 * fmaxf(acc[mi][ni][r] + bias, 0.f);
      }
    }
}

extern "C" void kernel_launch(void* const* d_in, const int* in_sizes, int n_in,
                              void* d_out, int out_size, void* d_ws, size_t ws_size,
                              hipStream_t stream) {
  const float* x   = (const float*)d_in[0];
  const float* shW = (const float*)d_in[1];
  const float* shb = (const float*)d_in[2];
  const float* tkW = (const float*)d_in[3];
  const float* tkb = (const float*)d_in[4];
  const float* gW  = (const float*)d_in[5];
  const float* gb  = (const float*)d_in[6];
  float* out = (float*)d_out;
  (void)in_sizes; (void)n_in; (void)out_size; (void)ws_size;

  char* ws = (char*)d_ws;
  __bf16* xb    = (__bf16*)(ws + XB_OFF);
  __bf16* wT    = (__bf16*)(ws + WT_OFF);
  float*  gates = (float*) (ws + GT_OFF);
  __bf16* shOut = (__bf16*)(ws + SH_OFF);

  cvt_inputs <<<dim3(24576), 256, 0, stream>>>(x, xb);
  cvt_weights<<<dim3(8, 16, 10), 256, 0, stream>>>(shW, tkW, wT);
  gates_kernel<<<dim3((TTASKS * BROWS) / 4), 256, 0, stream>>>(x, gW, gb, gates);

  shared_gemm8<<<dim3(BROWS / 256, ODIM / 128, 4), 512, 0, stream>>>(xb, wT, shb, shOut);
  taskA_gemm8 <<<dim3(BROWS / 256, ODIM / 128, TTASKS), 512, 0, stream>>>(xb, wT, tkb, gates,
                                                                          shOut, out);
  taskB_gemm8 <<<dim3(BROWS / 256, ODIM / 128, TTASKS), 512, 0, stream>>>(xb, wT, tkb, gates,
                                                                          out);
}

// Round 4
// 649.553 us; speedup vs baseline: 1.1202x; 1.1202x over previous
//
#include <hip/hip_runtime.h>
#include <hip/hip_bf16.h>
#include <stdint.h>

// PLE layer: T=3 tasks, B=16384 rows, I=1024, O=512, 4 shared + 2 task experts, 6 gates.
// Round 4: m97-style 2-barrier 128x128 MFMA core + T2 swizzle (proven, conflicts=0),
// single 32KB LDS buffer for occupancy overlap, task kernel split to cut AGPR pressure,
// gates read bf16 xb (half traffic).

#define TTASKS 3
#define BROWS  16384
#define KDIM   1024
#define ODIM   512
#define NGATE  6

typedef __attribute__((ext_vector_type(8))) __bf16 bf16x8;
typedef __attribute__((ext_vector_type(4))) float  f32x4;

// ---------------- ws layout (identical to rounds 2/3, 171 MiB, proven) ----------------
#define XB_OFF 0
#define WT_OFF 100663296UL
#define GT_OFF 111149056UL
#define SH_OFF 112328704UL

#define MFMA_(a, bb, c) __builtin_amdgcn_mfma_f32_16x16x32_bf16(a, bb, c, 0, 0, 0)

// ---------------- cvt inputs f32 -> bf16 ----------------
__global__ __launch_bounds__(256) void cvt_inputs(const float* __restrict__ x,
                                                  __bf16* __restrict__ xb) {
  size_t i = ((size_t)blockIdx.x * 256 + threadIdx.x) * 8;
  const float4* p = (const float4*)(x + i);
  float4 a = p[0], b = p[1];
  bf16x8 o = { (__bf16)a.x, (__bf16)a.y, (__bf16)a.z, (__bf16)a.w,
               (__bf16)b.x, (__bf16)b.y, (__bf16)b.z, (__bf16)b.w };
  *(bf16x8*)(xb + i) = o;
}

// ---------------- cvt + transpose weights: W[k][o] f32 -> wT[o][k] bf16 ----------------
__global__ __launch_bounds__(256) void cvt_weights(const float* __restrict__ shW,
                                                   const float* __restrict__ tkW,
                                                   __bf16* __restrict__ wT) {
  int s = blockIdx.z;
  const float* src = (s < 4) ? (shW + (size_t)s * KDIM * ODIM)
                             : (tkW + (size_t)(s - 4) * KDIM * ODIM);
  int o   = blockIdx.x * 64 + (threadIdx.x & 63);
  int sub = threadIdx.x >> 6;
#pragma unroll
  for (int kk = 0; kk < 2; ++kk) {
    int k0 = blockIdx.y * 64 + (sub * 2 + kk) * 8;
    bf16x8 v;
#pragma unroll
    for (int i = 0; i < 8; ++i)
      v[i] = (__bf16)src[(size_t)(k0 + i) * ODIM + o];
    *(bf16x8*)(wT + ((size_t)s * ODIM + o) * KDIM + k0) = v;
  }
}

// ---------------- gates from bf16 xb: one wave per (t,b) row ----------------
__global__ __launch_bounds__(256) void gates_kernel(const __bf16* __restrict__ xb,
                                                    const float* __restrict__ gW,
                                                    const float* __restrict__ gb,
                                                    float* __restrict__ gates) {
  int w = blockIdx.x * 4 + (threadIdx.x >> 6);
  int lane = threadIdx.x & 63;
  int t = w >> 14, b = w & (BROWS - 1);
  const __bf16* xr = xb + ((size_t)t * BROWS + b) * KDIM;
  const float* gw = gW + (size_t)t * KDIM * NGATE;
  float d[NGATE] = {0.f, 0.f, 0.f, 0.f, 0.f, 0.f};
#pragma unroll
  for (int i = 0; i < 2; ++i) {
    int k0 = (i * 64 + lane) * 8;                    // 8 consecutive k per lane
    bf16x8 xv = *(const bf16x8*)(xr + k0);
#pragma unroll
    for (int kk = 0; kk < 8; ++kk) {
      float xf = (float)xv[kk];
#pragma unroll
      for (int j = 0; j < NGATE; ++j) d[j] += xf * gw[(k0 + kk) * NGATE + j];
    }
  }
#pragma unroll
  for (int j = 0; j < NGATE; ++j) {
#pragma unroll
    for (int off = 32; off > 0; off >>= 1) d[j] += __shfl_xor(d[j], off, 64);
    d[j] += gb[t * NGATE + j];
  }
  float m = d[0];
#pragma unroll
  for (int j = 1; j < NGATE; ++j) m = fmaxf(m, d[j]);
  float s = 0.f;
#pragma unroll
  for (int j = 0; j < NGATE; ++j) { d[j] = expf(d[j] - m); s += d[j]; }
  float inv = 1.f / s;
  if (lane < NGATE) {
    float v = d[0];
#pragma unroll
    for (int j = 1; j < NGATE; ++j) v = (lane == j) ? d[j] : v;
    gates[(size_t)w * NGATE + lane] = v * inv;
  }
}

// ---------------- 128x128xK m97-style core, T2-swizzled, single 32KB buffer --------
// A rows: Ap[r*1024+k] r=0..127; B rows (= out cols): Bp[n*1024+k] n=0..127.
// 4 waves: wm=wv>>1, wn=wv&1; per-wave 64x64; acc[mi][ni] frag rows wm*64+mi*16, cols wn*64+ni*16.
// LDS slot (r, chunk c) holds global chunk c^(r&7); read applies same XOR (involution).
__device__ __forceinline__ void gemm_128(const __bf16* __restrict__ Ap,
                                         const __bf16* __restrict__ Bp,
                                         __bf16* As, __bf16* Bs,
                                         f32x4 acc[4][4]) {
  const int tid = threadIdx.x, lane = tid & 63, wv = tid >> 6;
  const int wm = wv >> 1, wn = wv & 1;
  const int lr = lane & 15, lg = lane >> 4, x7 = lr & 7;

  for (int kt = 0; kt < 16; ++kt) {
    const int k0 = kt * 64;
#pragma unroll
    for (int it = 0; it < 4; ++it) {
      const int idx = it * 256 + tid;            // 0..1023
      const int r   = idx >> 3;                  // row 0..127
      const int cs  = (idx & 7) ^ (r & 7);       // pre-swizzled 16B chunk
      __builtin_amdgcn_global_load_lds(
          (const __attribute__((address_space(1))) void*)(Ap + (size_t)r * KDIM + k0 + cs * 8),
          (__attribute__((address_space(3))) void*)(As + (it * 256 + wv * 64) * 8), 16, 0, 0);
      __builtin_amdgcn_global_load_lds(
          (const __attribute__((address_space(1))) void*)(Bp + (size_t)r * KDIM + k0 + cs * 8),
          (__attribute__((address_space(3))) void*)(Bs + (it * 256 + wv * 64) * 8), 16, 0, 0);
    }
    __syncthreads();   // drains vmcnt; staged tile visible

    const __bf16* aB = As + (wm * 64 + lr) * 64;
    const __bf16* bB = Bs + (wn * 64 + lr) * 64;
#pragma unroll
    for (int ks = 0; ks < 2; ++ks) {
      const int xo = ((ks * 4 + lg) ^ x7) * 8;
      bf16x8 af[4], bf[4];
#pragma unroll
      for (int mi = 0; mi < 4; ++mi) af[mi] = *(const bf16x8*)(aB + mi * 16 * 64 + xo);
#pragma unroll
      for (int ni = 0; ni < 4; ++ni) bf[ni] = *(const bf16x8*)(bB + ni * 16 * 64 + xo);
#pragma unroll
      for (int mi = 0; mi < 4; ++mi)
#pragma unroll
        for (int ni = 0; ni < 4; ++ni)
          acc[mi][ni] = MFMA_(af[mi], bf[ni], acc[mi][ni]);
    }
    __syncthreads();
  }
}

// ---------------- shared experts: relu(x0 @ W_e + b_e) -> bf16 ----------------
__global__ __launch_bounds__(256, 2) void shared_gemm(const __bf16* __restrict__ xb0,
                                                      const __bf16* __restrict__ wT,
                                                      const float* __restrict__ shb,
                                                      __bf16* __restrict__ shOut) {
  __shared__ __align__(16) __bf16 As[128 * 64], Bs[128 * 64];
  const int e = blockIdx.z;
  const int rowBase = blockIdx.x * 128, colBase = blockIdx.y * 128;
  const int tid = threadIdx.x, lane = tid & 63, wv = tid >> 6;
  const int wm = wv >> 1, wn = wv & 1, lr = lane & 15, lg = lane >> 4;

  f32x4 acc[4][4];
  f32x4 z = {0.f, 0.f, 0.f, 0.f};
#pragma unroll
  for (int mi = 0; mi < 4; ++mi)
#pragma unroll
    for (int ni = 0; ni < 4; ++ni) acc[mi][ni] = z;

  gemm_128(xb0 + (size_t)rowBase * KDIM,
           wT + ((size_t)e * ODIM + colBase) * KDIM, As, Bs, acc);

#pragma unroll
  for (int ni = 0; ni < 4; ++ni) {
    int col = colBase + wn * 64 + ni * 16 + lr;
    float bias = shb[e * ODIM + col];
#pragma unroll
    for (int mi = 0; mi < 4; ++mi)
#pragma unroll
      for (int r = 0; r < 4; ++r) {
        int row = rowBase + wm * 64 + mi * 16 + lg * 4 + r;
        float v = fmaxf(acc[mi][ni][r] + bias, 0.f);
        shOut[((size_t)e * BROWS + row) * ODIM + col] = (__bf16)v;
      }
  }
}

// ---------------- task expert 0 + gated combine with shared -> out (write) --------
__global__ __launch_bounds__(256, 2) void taskA_gemm(const __bf16* __restrict__ xb,
                                                     const __bf16* __restrict__ wT,
                                                     const float* __restrict__ tkb,
                                                     const float* __restrict__ gates,
                                                     const __bf16* __restrict__ shOut,
                                                     float* __restrict__ out) {
  __shared__ __align__(16) __bf16 As[128 * 64], Bs[128 * 64];
  const int t = blockIdx.z;
  const int rowBase = blockIdx.x * 128, colBase = blockIdx.y * 128;
  const int tid = threadIdx.x, lane = tid & 63, wv = tid >> 6;
  const int wm = wv >> 1, wn = wv & 1, lr = lane & 15, lg = lane >> 4;
  const size_t NB = (size_t)BROWS * ODIM;

  f32x4 acc[4][4];
  f32x4 z = {0.f, 0.f, 0.f, 0.f};
#pragma unroll
  for (int mi = 0; mi < 4; ++mi)
#pragma unroll
    for (int ni = 0; ni < 4; ++ni) acc[mi][ni] = z;

  gemm_128(xb + ((size_t)t * BROWS + rowBase) * KDIM,
           wT + ((size_t)(4 + t * 2) * ODIM + colBase) * KDIM, As, Bs, acc);

#pragma unroll
  for (int mi = 0; mi < 4; ++mi)
#pragma unroll
    for (int r = 0; r < 4; ++r) {
      int row = rowBase + wm * 64 + mi * 16 + lg * 4 + r;
      const float* gp = gates + ((size_t)t * BROWS + row) * NGATE;
      float g0 = gp[0], g1 = gp[1], g2 = gp[2], g3 = gp[3], g4 = gp[4];
#pragma unroll
      for (int ni = 0; ni < 4; ++ni) {
        int col = colBase + wn * 64 + ni * 16 + lr;
        size_t rc = (size_t)row * ODIM + col;
        float s = g0 * (float)shOut[rc] + g1 * (float)shOut[NB + rc] +
                  g2 * (float)shOut[2 * NB + rc] + g3 * (float)shOut[3 * NB + rc];
        float bias = tkb[(t * 2) * ODIM + col];
        s += g4 * fmaxf(acc[mi][ni][r] + bias, 0.f);
        out[((size_t)t * BROWS + row) * ODIM + col] = s;
      }
    }
}

// ---------------- task expert 1: out += g5 * relu(...) (RMW) ----------------
__global__ __launch_bounds__(256, 2) void taskB_gemm(const __bf16* __restrict__ xb,
                                                     const __bf16* __restrict__ wT,
                                                     const float* __restrict__ tkb,
                                                     const float* __restrict__ gates,
                                                     float* __restrict__ out) {
  __shared__ __align__(16) __bf16 As[128 * 64], Bs[128 * 64];
  const int t = blockIdx.z;
  const int rowBase = blockIdx.x * 128, colBase = blockIdx.y * 128;
  const int tid = threadIdx.x, lane = tid & 63, wv = tid >> 6;
  const int wm = wv >> 1, wn = wv & 1, lr = lane & 15, lg = lane >> 4;

  f32x4 acc[4][4];
  f32x4 z = {0.f, 0.f, 0.f, 0.f};
#pragma unroll
  for (int mi = 0; mi < 4; ++mi)
#pragma unroll
    for (int ni = 0; ni < 4; ++ni) acc[mi][ni] = z;

  gemm_128(xb + ((size_t)t * BROWS + rowBase) * KDIM,
           wT + ((size_t)(4 + t * 2 + 1) * ODIM + colBase) * KDIM, As, Bs, acc);

#pragma unroll
  for (int mi = 0; mi < 4; ++mi)
#pragma unroll
    for (int r = 0; r < 4; ++r) {
      int row = rowBase + wm * 64 + mi * 16 + lg * 4 + r;
      float g5 = gates[((size_t)t * BROWS + row) * NGATE + 5];
#pragma unroll
      for (int ni = 0; ni < 4; ++ni) {
        int col = colBase + wn * 64 + ni * 16 + lr;
        float bias = tkb[(t * 2 + 1) * ODIM + col];
        size_t oi = ((size_t)t * BROWS + row) * ODIM + col;
        out[oi] += g5 * fmaxf(acc[mi][ni][r] + bias, 0.f);
      }
    }
}

extern "C" void kernel_launch(void* const* d_in, const int* in_sizes, int n_in,
                              void* d_out, int out_size, void* d_ws, size_t ws_size,
                              hipStream_t stream) {
  const float* x   = (const float*)d_in[0];
  const float* shW = (const float*)d_in[1];
  const float* shb = (const float*)d_in[2];
  const float* tkW = (const float*)d_in[3];
  const float* tkb = (const float*)d_in[4];
  const float* gW  = (const float*)d_in[5];
  const float* gb  = (const float*)d_in[6];
  float* out = (float*)d_out;
  (void)in_sizes; (void)n_in; (void)out_size; (void)ws_size;

  char* ws = (char*)d_ws;
  __bf16* xb    = (__bf16*)(ws + XB_OFF);
  __bf16* wT    = (__bf16*)(ws + WT_OFF);
  float*  gates = (float*) (ws + GT_OFF);
  __bf16* shOut = (__bf16*)(ws + SH_OFF);

  cvt_inputs <<<dim3(24576), 256, 0, stream>>>(x, xb);
  cvt_weights<<<dim3(8, 16, 10), 256, 0, stream>>>(shW, tkW, wT);
  gates_kernel<<<dim3((TTASKS * BROWS) / 4), 256, 0, stream>>>(xb, gW, gb, gates);

  shared_gemm<<<dim3(BROWS / 128, ODIM / 128, 4), 256, 0, stream>>>(xb, wT, shb, shOut);
  taskA_gemm <<<dim3(BROWS / 128, ODIM / 128, TTASKS), 256, 0, stream>>>(xb, wT, tkb, gates,
                                                                         shOut, out);
  taskB_gemm <<<dim3(BROWS / 128, ODIM / 128, TTASKS), 256, 0, stream>>>(xb, wT, tkb, gates,
                                                                         out);
}